// Round 9
// baseline (130.031 us; speedup 1.0000x reference)
//
#include <hip/hip_runtime.h>
#include <hip/hip_bf16.h>

typedef __attribute__((ext_vector_type(8))) short short8;
typedef __attribute__((ext_vector_type(4))) float f32x4;

#define TEMP_INV 20.0f
#define NCH 1028

__device__ inline unsigned short f2bf(float f){
    unsigned int u = __builtin_bit_cast(unsigned int, f);
    u += 0x7fffu + ((u >> 16) & 1u);
    return (unsigned short)(u >> 16);
}
__device__ inline unsigned int pk2bf(float a, float b){
    return (unsigned int)f2bf(a) | ((unsigned int)f2bf(b) << 16);
}

// ---------------------------------------------------------------------------
// k_norm: normalize query rows -> bf16 A in LINEAR frag-major layout
// [kc][row][64] (A-frags are read straight from global/L2 by k_main, so no
// bank swizzle needed). Zeroes out[0] (k_lse atomicAdds into it).
// ---------------------------------------------------------------------------
__global__ __launch_bounds__(256) void k_norm(const float* __restrict__ q,
                                              unsigned short* __restrict__ Alin,
                                              float* __restrict__ out){
    int b = blockIdx.x, t = threadIdx.x;
    if (b == 0 && t == 0) out[0] = 0.f;
    const float* qr = q + b * 768;
    float v0 = qr[t], v1 = qr[t + 256], v2 = qr[t + 512];
    float ss = v0*v0 + v1*v1 + v2*v2;
#pragma unroll
    for (int o = 32; o; o >>= 1) ss += __shfl_xor(ss, o);
    __shared__ float red[4];
    if ((t & 63) == 0) red[t >> 6] = ss;
    __syncthreads();
    ss = red[0] + red[1] + red[2] + red[3];
    float inv = 1.0f / fmaxf(sqrtf(ss), 1e-8f);
    float nv[3] = {v0 * inv, v1 * inv, v2 * inv};
#pragma unroll
    for (int j = 0; j < 3; j++){
        int cc = t + 256 * j;
        Alin[(cc >> 6) * 16384 + b * 64 + (cc & 63)] = f2bf(nv[j]);
    }
}

// ---------------------------------------------------------------------------
// k_main: 1028 blocks x 512 threads (8 waves, acc[2][4]=32 AGPR, ~90 regs ->
// NO SPILL, 2 blocks/CU resident). Block b<1024: queue cols [64b,64b+64) vs
// all 256 queries. Blocks 1024..1027: keys cols (sim_pos + diag), same path.
// A-frags load directly from L2-resident Alin (no A LDS at all). B: f32 load
// -> ssq -> bf16 -> XOR-swizzled LDS, double-buffered, ONE barrier per kc.
// ---------------------------------------------------------------------------
__global__ __launch_bounds__(512, 4) void k_main(
        const float* __restrict__ keys,
        const float* __restrict__ queue,
        const unsigned short* __restrict__ Alin,
        float* __restrict__ pmax,
        float* __restrict__ psum,
        float* __restrict__ diag){
    __shared__ unsigned short Btile[2][4096]; // 16 KB dbuf [64][64] swizzled
    __shared__ float invn[64];
    __shared__ float redm[256];
    __shared__ float reds[256];

    const int b = blockIdx.x, t = threadIdx.x;
    const int lane = t & 63;
    const int w = t >> 6;                 // 0..7: wave-tile rows [32w,32w+32)
    const int frow = lane & 15, fg = lane >> 4;
    const int r = t >> 3, q8 = t & 7;     // B staging: 8 threads/row, 8 elems
    const bool keyb = (b >= 1024);
    const int cb = b - 1024;

    const float* src = keyb ? (keys + (cb * 64 + r) * 768)
                            : (queue + (size_t)(b * 64 + r) * 768);
    const float* rp = src + q8 * 8;

    float ssq = 0.f;
    f32x4 acc[2][4];
#pragma unroll
    for (int i = 0; i < 2; i++)
#pragma unroll
        for (int j = 0; j < 4; j++) acc[i][j] = (f32x4)0.f;

    // stage helper: 8 f32 -> ssq -> 8 bf16 -> one swizzled ds_write_b128
    auto stage = [&](unsigned short* bt, float4 u0, float4 u1){
        ssq += u0.x*u0.x + u0.y*u0.y + u0.z*u0.z + u0.w*u0.w;
        ssq += u1.x*u1.x + u1.y*u1.y + u1.z*u1.z + u1.w*u1.w;
        uint4 pk;
        pk.x = pk2bf(u0.x, u0.y); pk.y = pk2bf(u0.z, u0.w);
        pk.z = pk2bf(u1.x, u1.y); pk.w = pk2bf(u1.z, u1.w);
        int slot = q8 ^ (r & 7);
        *(uint4*)&bt[r * 64 + slot * 8] = pk;
    };

    // prologue: B(0) -> buf0; prefetch B(1) into regs
    float4 bA = *(const float4*)(rp);
    float4 bB = *(const float4*)(rp + 4);
    stage(Btile[0], bA, bB);
    bA = *(const float4*)(rp + 64);
    bB = *(const float4*)(rp + 68);
    __syncthreads();

#pragma unroll
    for (int kc = 0; kc < 12; ++kc){
        // write B(kc+1) into the other buffer (no race: reads use buf[kc&1])
        if (kc < 11) stage(Btile[(kc + 1) & 1], bA, bB);
        // prefetch B(kc+2) regs (latency hides under MFMA + barrier)
        if (kc < 10){
            bA = *(const float4*)(rp + (kc + 2) * 64);
            bB = *(const float4*)(rp + (kc + 2) * 64 + 4);
        }
        // MFMA on buf[kc&1]; A-frags straight from global (L2-hot Alin)
        const unsigned short* Bt = Btile[kc & 1];
#pragma unroll
        for (int ks = 0; ks < 2; ++ks){
            short8 af[2], bf4[4];
#pragma unroll
            for (int fm = 0; fm < 2; ++fm)
                af[fm] = *(const short8*)&Alin[kc * 16384 +
                         (w * 32 + fm * 16 + frow) * 64 + ks * 32 + fg * 8];
#pragma unroll
            for (int fn = 0; fn < 4; ++fn){
                int row = fn * 16 + frow;
                int slot = (ks * 4 + fg) ^ (row & 7);
                bf4[fn] = *(const short8*)&Bt[row * 64 + slot * 8];
            }
#pragma unroll
            for (int fm = 0; fm < 2; ++fm)
#pragma unroll
                for (int fn = 0; fn < 4; ++fn)
                    acc[fm][fn] = __builtin_amdgcn_mfma_f32_16x16x32_bf16(
                        af[fm], bf4[fn], acc[fm][fn], 0, 0, 0);
        }
        __syncthreads();
    }

    // ---- epilogue: B-col norms, scale, per-row max/sumexp (one wave/row) --
    ssq += __shfl_xor(ssq, 1);
    ssq += __shfl_xor(ssq, 2);
    ssq += __shfl_xor(ssq, 4);
    if (q8 == 0) invn[r] = 1.0f / fmaxf(sqrtf(ssq), 1e-8f);
    __syncthreads();

#pragma unroll
    for (int fm = 0; fm < 2; ++fm){
#pragma unroll
        for (int rr = 0; rr < 4; ++rr){
            int row = w * 32 + fm * 16 + fg * 4 + rr;
            float v[4];
#pragma unroll
            for (int fn = 0; fn < 4; ++fn){
                v[fn] = acc[fm][fn][rr] * invn[fn * 16 + frow] * TEMP_INV;
                if (keyb && row == cb * 64 + fn * 16 + frow) diag[row] = v[fn];
            }
            float m = fmaxf(fmaxf(v[0], v[1]), fmaxf(v[2], v[3]));
#pragma unroll
            for (int o = 1; o < 16; o <<= 1) m = fmaxf(m, __shfl_xor(m, o));
            float s = __expf(v[0]-m) + __expf(v[1]-m) + __expf(v[2]-m) + __expf(v[3]-m);
#pragma unroll
            for (int o = 1; o < 16; o <<= 1) s += __shfl_xor(s, o);
            if (frow == 0){ redm[row] = m; reds[row] = s; }
        }
    }
    __syncthreads();
    if (t < 256){
        pmax[b * 256 + t] = redm[t];
        psum[b * 256 + t] = reds[t];
    }
}

// ---------------------------------------------------------------------------
// k_lse: per q-row, merge 1028 chunk partials; atomicAdd loss contribution.
// ---------------------------------------------------------------------------
__global__ __launch_bounds__(256) void k_lse(const float* __restrict__ pmax,
                                             const float* __restrict__ psum,
                                             const float* __restrict__ diag,
                                             float* __restrict__ out){
    int b = blockIdx.x, t = threadIdx.x;
    float m = -1e30f;
    for (int cc = t; cc < NCH; cc += 256) m = fmaxf(m, pmax[cc * 256 + b]);
#pragma unroll
    for (int o = 32; o; o >>= 1) m = fmaxf(m, __shfl_xor(m, o));
    __shared__ float red[4];
    __shared__ float Msh;
    if ((t & 63) == 0) red[t >> 6] = m;
    __syncthreads();
    if (t == 0) Msh = fmaxf(fmaxf(red[0], red[1]), fmaxf(red[2], red[3]));
    __syncthreads();
    float M = Msh;
    float s = 0.f;
    for (int cc = t; cc < NCH; cc += 256) s += psum[cc * 256 + b] * __expf(pmax[cc * 256 + b] - M);
#pragma unroll
    for (int o = 32; o; o >>= 1) s += __shfl_xor(s, o);
    if ((t & 63) == 0) red[t >> 6] = s;
    __syncthreads();
    if (t == 0)
        atomicAdd(out, (M + logf(red[0] + red[1] + red[2] + red[3]) - diag[b]) * (1.0f / 256.0f));
}

extern "C" void kernel_launch(void* const* d_in, const int* in_sizes, int n_in,
                              void* d_out, int out_size, void* d_ws, size_t ws_size,
                              hipStream_t stream){
    const float* q  = (const float*)d_in[0];
    const float* k  = (const float*)d_in[1];
    const float* qu = (const float*)d_in[2];
    char* ws = (char*)d_ws;
    // ws layout (bytes): Alin 0..393216 | diag ..394240 |
    //                    pmax ..1446912 | psum ..2499584
    unsigned short* Alin = (unsigned short*)(ws);
    float* diag  = (float*)(ws + 393216);
    float* pmax  = (float*)(ws + 394240);
    float* psum  = (float*)(ws + 1446912);

    k_norm<<<256, 256, 0, stream>>>(q, Alin, (float*)d_out);
    k_main<<<1028, 512, 0, stream>>>(k, qu, Alin, pmax, psum, diag);
    k_lse<<<256, 256, 0, stream>>>(pmax, psum, diag, (float*)d_out);
}

// Round 10
// 90.713 us; speedup vs baseline: 1.4334x; 1.4334x over previous
//
#include <hip/hip_runtime.h>
#include <hip/hip_bf16.h>

typedef __attribute__((ext_vector_type(8))) short short8;
typedef __attribute__((ext_vector_type(4))) float f32x4;

#define TEMP_INV 20.0f
#define NCH 1028

__device__ inline unsigned short f2bf(float f){
    unsigned int u = __builtin_bit_cast(unsigned int, f);
    u += 0x7fffu + ((u >> 16) & 1u);
    return (unsigned short)(u >> 16);
}
__device__ inline unsigned int pk2bf(float a, float b){
    return (unsigned int)f2bf(a) | ((unsigned int)f2bf(b) << 16);
}

// ---------------------------------------------------------------------------
// k_norm: normalize query rows -> bf16 A in LINEAR frag-major layout
// [kc][row][64] (A-frags are read straight from global/L2 by k_main, so no
// bank swizzle needed). Zeroes out[0] (k_lse atomicAdds into it).
// ---------------------------------------------------------------------------
__global__ __launch_bounds__(256) void k_norm(const float* __restrict__ q,
                                              unsigned short* __restrict__ Alin,
                                              float* __restrict__ out){
    int b = blockIdx.x, t = threadIdx.x;
    if (b == 0 && t == 0) out[0] = 0.f;
    const float* qr = q + b * 768;
    float v0 = qr[t], v1 = qr[t + 256], v2 = qr[t + 512];
    float ss = v0*v0 + v1*v1 + v2*v2;
#pragma unroll
    for (int o = 32; o; o >>= 1) ss += __shfl_xor(ss, o);
    __shared__ float red[4];
    if ((t & 63) == 0) red[t >> 6] = ss;
    __syncthreads();
    ss = red[0] + red[1] + red[2] + red[3];
    float inv = 1.0f / fmaxf(sqrtf(ss), 1e-8f);
    float nv[3] = {v0 * inv, v1 * inv, v2 * inv};
#pragma unroll
    for (int j = 0; j < 3; j++){
        int cc = t + 256 * j;
        Alin[(cc >> 6) * 16384 + b * 64 + (cc & 63)] = f2bf(nv[j]);
    }
}

// ---------------------------------------------------------------------------
// k_main: 1028 blocks x 512 threads (8 waves, acc[2][4]=32 AGPR, ~96 unified
// regs -> NO SPILL target, 2 blocks/CU). Block b<1024: queue cols
// [64b,64b+64) vs all 256 queries. Blocks 1024..1027: keys cols (sim_pos +
// diag), same path. A-frags load directly from L2-resident Alin (no A LDS).
// B: f32 load -> ssq -> bf16 -> XOR-swizzled LDS, double-buffered, ONE
// barrier per kc. kc loop kept rolled (#pragma unroll 1): full unroll in R9
// hoisted 12 iterations of global loads -> ~200 B/thread scratch spill
// (WRITE_SIZE 109 MB, 160 us). Do not re-unroll.
// ---------------------------------------------------------------------------
__global__ __launch_bounds__(512, 4) void k_main(
        const float* __restrict__ keys,
        const float* __restrict__ queue,
        const unsigned short* __restrict__ Alin,
        float* __restrict__ pmax,
        float* __restrict__ psum,
        float* __restrict__ diag){
    __shared__ unsigned short Btile[2][4096]; // 16 KB dbuf [64][64] swizzled
    __shared__ float invn[64];
    __shared__ float redm[256];
    __shared__ float reds[256];

    const int b = blockIdx.x, t = threadIdx.x;
    const int lane = t & 63;
    const int w = t >> 6;                 // 0..7: wave-tile rows [32w,32w+32)
    const int frow = lane & 15, fg = lane >> 4;
    const int r = t >> 3, q8 = t & 7;     // B staging: 8 threads/row, 8 elems
    const bool keyb = (b >= 1024);
    const int cb = b - 1024;

    const float* src = keyb ? (keys + (cb * 64 + r) * 768)
                            : (queue + (size_t)(b * 64 + r) * 768);
    const float* rp = src + q8 * 8;

    float ssq = 0.f;
    f32x4 acc[2][4];
#pragma unroll
    for (int i = 0; i < 2; i++)
#pragma unroll
        for (int j = 0; j < 4; j++) acc[i][j] = (f32x4)0.f;

    // stage helper: 8 f32 -> ssq -> 8 bf16 -> one swizzled ds_write_b128
    auto stage = [&](unsigned short* bt, float4 u0, float4 u1){
        ssq += u0.x*u0.x + u0.y*u0.y + u0.z*u0.z + u0.w*u0.w;
        ssq += u1.x*u1.x + u1.y*u1.y + u1.z*u1.z + u1.w*u1.w;
        uint4 pk;
        pk.x = pk2bf(u0.x, u0.y); pk.y = pk2bf(u0.z, u0.w);
        pk.z = pk2bf(u1.x, u1.y); pk.w = pk2bf(u1.z, u1.w);
        int slot = q8 ^ (r & 7);
        *(uint4*)&bt[r * 64 + slot * 8] = pk;
    };

    // prologue: B(0) -> buf0; prefetch B(1) into regs
    float4 bA = *(const float4*)(rp);
    float4 bB = *(const float4*)(rp + 4);
    stage(Btile[0], bA, bB);
    bA = *(const float4*)(rp + 64);
    bB = *(const float4*)(rp + 68);
    __syncthreads();

#pragma unroll 1
    for (int kc = 0; kc < 12; ++kc){
        // write B(kc+1) into the other buffer (no race: reads use buf[kc&1])
        if (kc < 11) stage(Btile[(kc + 1) & 1], bA, bB);
        // prefetch B(kc+2) regs (latency hides under MFMA + barrier)
        if (kc < 10){
            bA = *(const float4*)(rp + (kc + 2) * 64);
            bB = *(const float4*)(rp + (kc + 2) * 64 + 4);
        }
        // MFMA on buf[kc&1]; A-frags straight from global (L2-hot Alin)
        const unsigned short* Bt = Btile[kc & 1];
#pragma unroll
        for (int ks = 0; ks < 2; ++ks){
            short8 af[2], bf4[4];
#pragma unroll
            for (int fm = 0; fm < 2; ++fm)
                af[fm] = *(const short8*)&Alin[kc * 16384 +
                         (w * 32 + fm * 16 + frow) * 64 + ks * 32 + fg * 8];
#pragma unroll
            for (int fn = 0; fn < 4; ++fn){
                int row = fn * 16 + frow;
                int slot = (ks * 4 + fg) ^ (row & 7);
                bf4[fn] = *(const short8*)&Bt[row * 64 + slot * 8];
            }
#pragma unroll
            for (int fm = 0; fm < 2; ++fm)
#pragma unroll
                for (int fn = 0; fn < 4; ++fn)
                    acc[fm][fn] = __builtin_amdgcn_mfma_f32_16x16x32_bf16(
                        af[fm], bf4[fn], acc[fm][fn], 0, 0, 0);
        }
        __syncthreads();
    }

    // ---- epilogue: B-col norms, scale, per-row max/sumexp (one wave/row) --
    ssq += __shfl_xor(ssq, 1);
    ssq += __shfl_xor(ssq, 2);
    ssq += __shfl_xor(ssq, 4);
    if (q8 == 0) invn[r] = 1.0f / fmaxf(sqrtf(ssq), 1e-8f);
    __syncthreads();

#pragma unroll
    for (int fm = 0; fm < 2; ++fm){
#pragma unroll
        for (int rr = 0; rr < 4; ++rr){
            int row = w * 32 + fm * 16 + fg * 4 + rr;
            float v[4];
#pragma unroll
            for (int fn = 0; fn < 4; ++fn){
                v[fn] = acc[fm][fn][rr] * invn[fn * 16 + frow] * TEMP_INV;
                if (keyb && row == cb * 64 + fn * 16 + frow) diag[row] = v[fn];
            }
            float m = fmaxf(fmaxf(v[0], v[1]), fmaxf(v[2], v[3]));
#pragma unroll
            for (int o = 1; o < 16; o <<= 1) m = fmaxf(m, __shfl_xor(m, o));
            float s = __expf(v[0]-m) + __expf(v[1]-m) + __expf(v[2]-m) + __expf(v[3]-m);
#pragma unroll
            for (int o = 1; o < 16; o <<= 1) s += __shfl_xor(s, o);
            if (frow == 0){ redm[row] = m; reds[row] = s; }
        }
    }
    __syncthreads();
    if (t < 256){
        pmax[b * 256 + t] = redm[t];
        psum[b * 256 + t] = reds[t];
    }
}

// ---------------------------------------------------------------------------
// k_lse: per q-row, merge 1028 chunk partials; atomicAdd loss contribution.
// ---------------------------------------------------------------------------
__global__ __launch_bounds__(256) void k_lse(const float* __restrict__ pmax,
                                             const float* __restrict__ psum,
                                             const float* __restrict__ diag,
                                             float* __restrict__ out){
    int b = blockIdx.x, t = threadIdx.x;
    float m = -1e30f;
    for (int cc = t; cc < NCH; cc += 256) m = fmaxf(m, pmax[cc * 256 + b]);
#pragma unroll
    for (int o = 32; o; o >>= 1) m = fmaxf(m, __shfl_xor(m, o));
    __shared__ float red[4];
    __shared__ float Msh;
    if ((t & 63) == 0) red[t >> 6] = m;
    __syncthreads();
    if (t == 0) Msh = fmaxf(fmaxf(red[0], red[1]), fmaxf(red[2], red[3]));
    __syncthreads();
    float M = Msh;
    float s = 0.f;
    for (int cc = t; cc < NCH; cc += 256) s += psum[cc * 256 + b] * __expf(pmax[cc * 256 + b] - M);
#pragma unroll
    for (int o = 32; o; o >>= 1) s += __shfl_xor(s, o);
    if ((t & 63) == 0) red[t >> 6] = s;
    __syncthreads();
    if (t == 0)
        atomicAdd(out, (M + logf(red[0] + red[1] + red[2] + red[3]) - diag[b]) * (1.0f / 256.0f));
}

extern "C" void kernel_launch(void* const* d_in, const int* in_sizes, int n_in,
                              void* d_out, int out_size, void* d_ws, size_t ws_size,
                              hipStream_t stream){
    const float* q  = (const float*)d_in[0];
    const float* k  = (const float*)d_in[1];
    const float* qu = (const float*)d_in[2];
    char* ws = (char*)d_ws;
    // ws layout (bytes): Alin 0..393216 | diag ..394240 |
    //                    pmax ..1446912 | psum ..2499584
    unsigned short* Alin = (unsigned short*)(ws);
    float* diag  = (float*)(ws + 393216);
    float* pmax  = (float*)(ws + 394240);
    float* psum  = (float*)(ws + 1446912);

    k_norm<<<256, 256, 0, stream>>>(q, Alin, (float*)d_out);
    k_main<<<1028, 512, 0, stream>>>(k, qu, Alin, pmax, psum, diag);
    k_lse<<<256, 256, 0, stream>>>(pmax, psum, diag, (float*)d_out);
}